// Round 1
// baseline (797.774 us; speedup 1.0000x reference)
//
#include <hip/hip_runtime.h>
#include <hip/hip_bf16.h>
#include <stdint.h>

#define T_DIM 256
#define B_DIM 64
#define DICO  8192
#define EMB   256
#define LAT   256
#define M_DIM (T_DIM*B_DIM)   /* 16384 */

#define BM 64
#define BN 256
#define BK 64
#define KSPLIT 2
#define KCHUNK (DICO/KSPLIT)  /* 4096 */

typedef short  bf16x8 __attribute__((ext_vector_type(8)));
typedef float  f32x4  __attribute__((ext_vector_type(4)));
typedef _Float16 f16x2 __attribute__((ext_vector_type(2)));

__device__ __forceinline__ ushort f2bf(float f) {
  uint32_t u = __float_as_uint(f);
  u += 0x7FFFu + ((u >> 16) & 1u);     // round-to-nearest-even
  return (ushort)(u >> 16);
}

__device__ __forceinline__ void glds16(const void* g, void* l) {
  __builtin_amdgcn_global_load_lds(
      (const __attribute__((address_space(1))) uint32_t*)g,
      (__attribute__((address_space(3))) uint32_t*)l, 16, 0, 0);
}

// ---------------- Kernel 1: Wct[n][k] = sum_e W_emb[k][e] * W_enc[e][n], bf16, n-major
__global__ void wct_kernel(const float* __restrict__ Wemb, const float* __restrict__ Wenc,
                           ushort* __restrict__ wct) {
  const int n  = threadIdx.x;          // 0..255
  const int d0 = blockIdx.x * 32;      // 256 blocks
  __shared__ float we[32 * 256];
  __shared__ float tr[32 * 257];
  #pragma unroll
  for (int r = 0; r < 32; ++r) we[r*256 + n] = Wemb[(size_t)(d0 + r)*EMB + n];
  __syncthreads();
  float acc[32];
  #pragma unroll
  for (int d = 0; d < 32; ++d) acc[d] = 0.f;
  for (int e = 0; e < 256; ++e) {
    float wv = Wenc[e*LAT + n];
    #pragma unroll
    for (int d = 0; d < 32; ++d) acc[d] += we[d*256 + e] * wv;   // LDS broadcast
  }
  #pragma unroll
  for (int d = 0; d < 32; ++d) tr[d*257 + n] = acc[d];
  __syncthreads();
  const int nn0 = n >> 2, kc = n & 3;
  #pragma unroll
  for (int p = 0; p < 4; ++p) {
    int nn = p*64 + nn0;
    bf16x8 v;
    #pragma unroll
    for (int j = 0; j < 8; ++j) v[j] = (short)f2bf(tr[(kc*8 + j)*257 + nn]);
    *(bf16x8*)(wct + (size_t)nn*DICO + d0 + kc*8) = v;
  }
}

// ---------------- Kernel 2: xp_part[ksp] = x[:, kchunk] @ Wc[kchunk, :]
__global__ void __launch_bounds__(256) gemm_kernel(const float* __restrict__ x,
                                                   const ushort* __restrict__ wct,
                                                   float* __restrict__ xp) {
  __shared__ __align__(16) ushort sA[BM * 72];    // 64 rows, 64 k + 8 pad
  __shared__ __align__(16) ushort sB[BN * BK];    // 256 n-rows x 64 k, linear
  const int tid = threadIdx.x;
  const int bid = blockIdx.x;
  const int swzb = (bid & 7)*64 + (bid >> 3);     // XCD-contiguous (512 % 8 == 0)
  const int mt  = swzb & 255, ksp = swzb >> 8;
  const size_t rowbase = (size_t)mt * BM;
  const int kbase = ksp * KCHUNK;

  const int lane = tid & 63, wid = tid >> 6;
  const int l15 = lane & 15, lc = lane >> 4;

  const int arow = tid >> 2, akc = tid & 3;       // A staging: 64 rows x 4 chunks of 16 floats
  const float* ag = x + rowbase*(size_t)DICO + (size_t)arow*DICO + kbase + akc*16;
  const char*  wb = (const char*)wct;
  const size_t kb2 = (size_t)kbase * 2;

  f32x4 acc[4][4];
  #pragma unroll
  for (int m = 0; m < 4; ++m)
    #pragma unroll
    for (int n = 0; n < 4; ++n) acc[m][n] = (f32x4){0.f,0.f,0.f,0.f};

  for (int ks = 0; ks < KCHUNK/BK; ++ks) {
    const int kofs = ks*BK;
    // A global loads (fp32) — issue before barrier
    float4 av0 = *(const float4*)(ag + kofs);
    float4 av1 = *(const float4*)(ag + kofs + 4);
    float4 av2 = *(const float4*)(ag + kofs + 8);
    float4 av3 = *(const float4*)(ag + kofs + 12);
    __syncthreads();                               // prior K-step's LDS reads done
    bf16x8 w0, w1;
    w0[0]=(short)f2bf(av0.x); w0[1]=(short)f2bf(av0.y); w0[2]=(short)f2bf(av0.z); w0[3]=(short)f2bf(av0.w);
    w0[4]=(short)f2bf(av1.x); w0[5]=(short)f2bf(av1.y); w0[6]=(short)f2bf(av1.z); w0[7]=(short)f2bf(av1.w);
    w1[0]=(short)f2bf(av2.x); w1[1]=(short)f2bf(av2.y); w1[2]=(short)f2bf(av2.z); w1[3]=(short)f2bf(av2.w);
    w1[4]=(short)f2bf(av3.x); w1[5]=(short)f2bf(av3.y); w1[6]=(short)f2bf(av3.z); w1[7]=(short)f2bf(av3.w);
    *(bf16x8*)(sA + arow*72 + akc*16)     = w0;
    *(bf16x8*)(sA + arow*72 + akc*16 + 8) = w1;
    // B: global_load_lds direct, 8 rounds x 16B/thread = 32 KB
    #pragma unroll
    for (int r = 0; r < 8; ++r) {
      int o = r*4096 + tid*16;                     // linear byte offset in sB
      int n = o >> 7, rb = o & 127;
      glds16(wb + (size_t)n*(DICO*2) + kb2 + (size_t)(kofs*2) + rb, (char*)sB + o);
    }
    __syncthreads();                               // drains vmcnt+lgkm (compiler)
    bf16x8 a[4][2], b[4][2];
    #pragma unroll
    for (int m = 0; m < 4; ++m)
      #pragma unroll
      for (int k2 = 0; k2 < 2; ++k2)
        a[m][k2] = *(const bf16x8*)(sA + (m*16 + l15)*72 + k2*32 + lc*8);
    #pragma unroll
    for (int n = 0; n < 4; ++n)
      #pragma unroll
      for (int k2 = 0; k2 < 2; ++k2)
        b[n][k2] = *(const bf16x8*)(sB + (wid*64 + n*16 + l15)*64 + k2*32 + lc*8);
    #pragma unroll
    for (int m = 0; m < 4; ++m)
      #pragma unroll
      for (int n = 0; n < 4; ++n)
        #pragma unroll
        for (int k2 = 0; k2 < 2; ++k2)
          acc[m][n] = __builtin_amdgcn_mfma_f32_16x16x32_bf16(a[m][k2], b[n][k2], acc[m][n], 0, 0, 0);
  }
  float* xpo = xp + ((size_t)ksp*M_DIM + rowbase) * LAT;
  #pragma unroll
  for (int m = 0; m < 4; ++m)
    #pragma unroll
    for (int n = 0; n < 4; ++n)
      #pragma unroll
      for (int j = 0; j < 4; ++j)
        xpo[(size_t)(m*16 + lc*4 + j)*LAT + wid*64 + n*16 + l15] = acc[m][n][j];
}

// ---------------- Kernel 3: per-b recurrence h = tanh(xp_t + bc + h@Wh)
__global__ void rnn_kernel(const float* __restrict__ xp, const float* __restrict__ h0,
                           const float* __restrict__ Wenc, const float* __restrict__ bemb,
                           const float* __restrict__ benc, float* __restrict__ out) {
  const int b = blockIdx.x, l = threadIdx.x;       // 64 blocks x 256 threads
  __shared__ __align__(16) uint32_t h2[128];       // 256 halves of h
  // bc[l] = b_emb @ Wx + b_enc
  float bc = benc[l];
  for (int e = 0; e < 256; ++e) bc += bemb[e] * Wenc[e*LAT + l];
  // Wh column l in 128 packed-f16x2 registers (statically indexed)
  f16x2 wh[128];
  #pragma unroll
  for (int j = 0; j < 128; ++j) {
    float w0 = Wenc[(size_t)(EMB + 2*j    )*LAT + l];
    float w1 = Wenc[(size_t)(EMB + 2*j + 1)*LAT + l];
    f16x2 w; w[0] = (_Float16)w0; w[1] = (_Float16)w1;
    wh[j] = w;
  }
  ((_Float16*)h2)[l] = (_Float16)h0[(size_t)b*LAT + l];
  __syncthreads();
  const float* xpb = xp + (size_t)b*LAT + l;
  float*       ob  = out + (size_t)b*LAT + l;
  for (int t = 0; t < T_DIM; ++t) {
    size_t idx = (size_t)t * B_DIM * LAT;
    float xv = xpb[idx] + xpb[idx + (size_t)M_DIM*LAT];   // two K-split partials
    float a0 = 0.f, a1 = 0.f, a2 = 0.f, a3 = 0.f;
    #pragma unroll
    for (int jj = 0; jj < 32; ++jj) {
      uint4 hv = *(const uint4*)(h2 + jj*4);              // LDS broadcast
      a0 = __builtin_amdgcn_fdot2(wh[jj*4+0], __builtin_bit_cast(f16x2, hv.x), a0, false);
      a1 = __builtin_amdgcn_fdot2(wh[jj*4+1], __builtin_bit_cast(f16x2, hv.y), a1, false);
      a2 = __builtin_amdgcn_fdot2(wh[jj*4+2], __builtin_bit_cast(f16x2, hv.z), a2, false);
      a3 = __builtin_amdgcn_fdot2(wh[jj*4+3], __builtin_bit_cast(f16x2, hv.w), a3, false);
    }
    float pre = xv + bc + ((a0 + a1) + (a2 + a3));
    float ax = fabsf(pre);
    float e  = __expf(-2.f * ax);                          // in (0,1], no overflow
    float r  = (1.f - e) / (1.f + e);
    float hn = (pre < 0.f) ? -r : r;
    ob[idx] = hn;
    __syncthreads();                                       // all reads of h2 done
    ((_Float16*)h2)[l] = (_Float16)hn;
    __syncthreads();                                       // h2 ready for next step
  }
}

extern "C" void kernel_launch(void* const* d_in, const int* in_sizes, int n_in,
                              void* d_out, int out_size, void* d_ws, size_t ws_size,
                              hipStream_t stream) {
  const float* x    = (const float*)d_in[0];
  const float* h0   = (const float*)d_in[1];
  const float* Wemb = (const float*)d_in[2];
  const float* bemb = (const float*)d_in[3];
  const float* Wenc = (const float*)d_in[4];
  const float* benc = (const float*)d_in[5];
  float* out = (float*)d_out;

  ushort* wct = (ushort*)d_ws;                               // 4 MiB bf16 [256][8192]
  float*  xp  = (float*)((char*)d_ws + ((size_t)4 << 20));   // 2 x 16 MiB fp32 partials

  wct_kernel<<<256, 256, 0, stream>>>(Wemb, Wenc, wct);
  gemm_kernel<<<512, 256, 0, stream>>>(x, wct, xp);
  rnn_kernel<<<64, 256, 0, stream>>>(xp, h0, Wenc, bemb, benc, out);
}

// Round 2
// 577.663 us; speedup vs baseline: 1.3810x; 1.3810x over previous
//
#include <hip/hip_runtime.h>
#include <hip/hip_bf16.h>
#include <stdint.h>

#define T_DIM 256
#define B_DIM 64
#define DICO  8192
#define EMB   256
#define LAT   256
#define M_DIM (T_DIM*B_DIM)   /* 16384 */

#define BM 128
#define BN 256
#define BK 64
#define KSPLIT 2
#define KCHUNK (DICO/KSPLIT)  /* 4096 */
#define NKS (KCHUNK/BK)       /* 64 */

typedef short  bf16x8 __attribute__((ext_vector_type(8)));
typedef float  f32x4  __attribute__((ext_vector_type(4)));
typedef _Float16 f16x2 __attribute__((ext_vector_type(2)));

__device__ __forceinline__ ushort f2bf(float f) {
  uint32_t u = __float_as_uint(f);
  u += 0x7FFFu + ((u >> 16) & 1u);     // round-to-nearest-even
  return (ushort)(u >> 16);
}

__device__ __forceinline__ void glds16(const void* g, void* l) {
  __builtin_amdgcn_global_load_lds(
      (const __attribute__((address_space(1))) uint32_t*)g,
      (__attribute__((address_space(3))) uint32_t*)l, 16, 0, 0);
}

// ---------------- Kernel 1: Wct[n][k] = sum_e W_emb[k][e] * W_enc[e][n], bf16, n-major
__global__ void wct_kernel(const float* __restrict__ Wemb, const float* __restrict__ Wenc,
                           ushort* __restrict__ wct) {
  const int n  = threadIdx.x;          // 0..255
  const int d0 = blockIdx.x * 32;      // 256 blocks
  __shared__ float we[32 * 256];
  __shared__ float tr[32 * 257];
  #pragma unroll
  for (int r = 0; r < 32; ++r) we[r*256 + n] = Wemb[(size_t)(d0 + r)*EMB + n];
  __syncthreads();
  float acc[32];
  #pragma unroll
  for (int d = 0; d < 32; ++d) acc[d] = 0.f;
  for (int e = 0; e < 256; ++e) {
    float wv = Wenc[e*LAT + n];
    #pragma unroll
    for (int d = 0; d < 32; ++d) acc[d] += we[d*256 + e] * wv;   // LDS broadcast
  }
  #pragma unroll
  for (int d = 0; d < 32; ++d) tr[d*257 + n] = acc[d];
  __syncthreads();
  const int nn0 = n >> 2, kc = n & 3;
  #pragma unroll
  for (int p = 0; p < 4; ++p) {
    int nn = p*64 + nn0;
    bf16x8 v;
    #pragma unroll
    for (int j = 0; j < 8; ++j) v[j] = (short)f2bf(tr[(kc*8 + j)*257 + nn]);
    *(bf16x8*)(wct + (size_t)nn*DICO + d0 + kc*8) = v;
  }
}

// ---------------- Kernel 2: xp_part[ksp] = x[:, kchunk] @ Wc[kchunk, :]
// 2-phase pipeline: STAGE(t+1) -> compute(t) -> barrier. Fragment-ordered LDS
// (lane-linear ds_read_b128, conflict-free). B staged via global_load_lds with
// pre-swizzled source addresses (m173 pattern); A reg-staged (fp32->bf16) with
// issue-early / write-late (T14).
__global__ void __launch_bounds__(256, 2) gemm_kernel(const float* __restrict__ x,
                                                      const ushort* __restrict__ wct,
                                                      float* __restrict__ xp) {
  __shared__ __align__(16) ushort sA[2][BM * BK];   // frag-order, 16 KB each
  __shared__ __align__(16) ushort sB[2][BN * BK];   // frag-order, 32 KB each
  const int tid = threadIdx.x;
  const int bid = blockIdx.x;                        // 256 blocks
  const int swzb = (bid & 7) * 32 + (bid >> 3);      // XCD-contiguous (256%8==0)
  const int mt = swzb & 127, ksp = swzb >> 7;        // same-XCD blocks share ksp (B L2-resident)
  const size_t rowbase = (size_t)mt * BM;
  const int kbase = ksp * KCHUNK;

  const int lane = tid & 63, wid = tid >> 6;
  const int l15 = lane & 15, lc = lane >> 4;

  // A staging: thread owns segments tid and tid+256; seg s: row=s>>2, 16-float chunk=s&3
  const int r0 = tid >> 2, c0 = tid & 3;
  const float* ag0 = x + (rowbase + r0) * (size_t)DICO + kbase + c0 * 16;
  const float* ag1 = ag0 + (size_t)64 * DICO;
  // frag-order dst: group=(row>>4)*2+(chunk>>1), lane_slot=(row&15)+(chunk&1)*32 (+16 for hi 8)
  const int aw0 = ((((r0      ) >> 4) * 2 + (c0 >> 1)) * 64 + (r0 & 15) + (c0 & 1) * 32) * 16;
  const int aw1 = ((((r0 + 64 ) >> 4) * 2 + (c0 >> 1)) * 64 + (r0 & 15) + (c0 & 1) * 32) * 16;

  const char* wb = (const char*)wct;
  const size_t kb2 = (size_t)kbase * 2;

  f32x4 acc[8][4];
  #pragma unroll
  for (int m = 0; m < 8; ++m)
    #pragma unroll
    for (int n = 0; n < 4; ++n) acc[m][n] = (f32x4){0.f, 0.f, 0.f, 0.f};

  float4 av[8];

  auto loadA = [&](int kofs) {
    #pragma unroll
    for (int q = 0; q < 4; ++q) av[q]     = *(const float4*)(ag0 + kofs + q * 4);
    #pragma unroll
    for (int q = 0; q < 4; ++q) av[4 + q] = *(const float4*)(ag1 + kofs + q * 4);
  };
  auto stageB = [&](int buf, int kofs) {
    // group g=r*4+wid holds (nfrag=g>>1, k2=g&1); lane l: col16=l&15 -> wct row, lc -> k sub-8
    #pragma unroll
    for (int r = 0; r < 8; ++r) {
      const int g = r * 4 + wid;
      const int srow  = (g >> 1) * 16 + l15;
      const int skoff = (g & 1) * 32 + lc * 8;
      glds16(wb + (size_t)srow * (DICO * 2) + kb2 + (size_t)(kofs + skoff) * 2,
             (char*)&sB[buf][0] + r * 4096 + tid * 16);
    }
  };
  auto storeA = [&](int buf) {
    #pragma unroll
    for (int h = 0; h < 2; ++h) {
      const float4 a0 = av[h*4+0], a1 = av[h*4+1], a2 = av[h*4+2], a3 = av[h*4+3];
      bf16x8 w0, w1;
      w0[0]=(short)f2bf(a0.x); w0[1]=(short)f2bf(a0.y); w0[2]=(short)f2bf(a0.z); w0[3]=(short)f2bf(a0.w);
      w0[4]=(short)f2bf(a1.x); w0[5]=(short)f2bf(a1.y); w0[6]=(short)f2bf(a1.z); w0[7]=(short)f2bf(a1.w);
      w1[0]=(short)f2bf(a2.x); w1[1]=(short)f2bf(a2.y); w1[2]=(short)f2bf(a2.z); w1[3]=(short)f2bf(a2.w);
      w1[4]=(short)f2bf(a3.x); w1[5]=(short)f2bf(a3.y); w1[6]=(short)f2bf(a3.z); w1[7]=(short)f2bf(a3.w);
      char* base = (char*)&sA[buf][0] + (h ? aw1 : aw0);
      *(bf16x8*)(base)       = w0;
      *(bf16x8*)(base + 256) = w1;
    }
  };
  auto compute = [&](int buf) {
    bf16x8 bfr[4][2];
    #pragma unroll
    for (int n = 0; n < 4; ++n)
      #pragma unroll
      for (int k2 = 0; k2 < 2; ++k2)
        bfr[n][k2] = *(const bf16x8*)((char*)&sB[buf][0] + ((((wid*4 + n)*2 + k2) * 64 + lane) * 16));
    #pragma unroll
    for (int m = 0; m < 8; ++m) {
      bf16x8 a0 = *(const bf16x8*)((char*)&sA[buf][0] + (((m*2 + 0) * 64 + lane) * 16));
      bf16x8 a1 = *(const bf16x8*)((char*)&sA[buf][0] + (((m*2 + 1) * 64 + lane) * 16));
      #pragma unroll
      for (int n = 0; n < 4; ++n) {
        acc[m][n] = __builtin_amdgcn_mfma_f32_16x16x32_bf16(a0, bfr[n][0], acc[m][n], 0, 0, 0);
        acc[m][n] = __builtin_amdgcn_mfma_f32_16x16x32_bf16(a1, bfr[n][1], acc[m][n], 0, 0, 0);
      }
    }
  };

  // prologue
  loadA(0);
  stageB(0, 0);
  storeA(0);
  __syncthreads();

  int cur = 0;
  for (int ks = 0; ks < NKS; ++ks) {
    const int kn = (ks + 1) * BK;
    if (ks + 1 < NKS) { loadA(kn); stageB(cur ^ 1, kn); }  // issue-early
    compute(cur);
    if (ks + 1 < NKS) storeA(cur ^ 1);                      // write-late (vmcnt waits here)
    __syncthreads();
    cur ^= 1;
  }

  float* xpo = xp + ((size_t)ksp * M_DIM + rowbase) * LAT;
  #pragma unroll
  for (int m = 0; m < 8; ++m)
    #pragma unroll
    for (int n = 0; n < 4; ++n)
      #pragma unroll
      for (int j = 0; j < 4; ++j)
        xpo[(size_t)(m*16 + lc*4 + j) * LAT + wid*64 + n*16 + l15] = acc[m][n][j];
}

// ---------------- Kernel 3: per-b recurrence h = tanh(xp_t + bc + h@Wh)
// launch_bounds(256,1): 1 block/CU anyway (64 blocks) -> un-cap VGPRs so wh[128]
// stays in registers (round-1 VGPR_Count=64 proved it spilled to scratch).
__global__ void __launch_bounds__(256, 1) rnn_kernel(const float* __restrict__ xp,
                           const float* __restrict__ h0, const float* __restrict__ Wenc,
                           const float* __restrict__ bemb, const float* __restrict__ benc,
                           float* __restrict__ out) {
  const int b = blockIdx.x, l = threadIdx.x;       // 64 blocks x 256 threads
  __shared__ __align__(16) uint32_t hbuf[2][128];  // double-buffered h (f16) -> 1 barrier/step
  float bc = benc[l];
  for (int e = 0; e < 256; ++e) bc += bemb[e] * Wenc[e*LAT + l];
  f16x2 wh[128];
  #pragma unroll
  for (int j = 0; j < 128; ++j) {
    f16x2 w;
    w[0] = (_Float16)Wenc[(size_t)(EMB + 2*j    )*LAT + l];
    w[1] = (_Float16)Wenc[(size_t)(EMB + 2*j + 1)*LAT + l];
    wh[j] = w;
  }
  ((_Float16*)&hbuf[0][0])[l] = (_Float16)h0[(size_t)b*LAT + l];
  __syncthreads();
  const float* xpb = xp + (size_t)b*LAT + l;
  float*       ob  = out + (size_t)b*LAT + l;
  const size_t ST = (size_t)B_DIM * LAT;           // 16384
  const size_t PO = (size_t)M_DIM * LAT;           // partial offset
  // 2-step-ahead register prefetch of xp (ping-pong scalars, no arrays)
  float xa0 = xpb[0],  xa1 = xpb[PO];
  float xb0 = xpb[ST], xb1 = xpb[ST + PO];
  float xc0 = 0.f, xc1 = 0.f;
  for (int t = 0; t < T_DIM; ++t) {
    if (t + 2 < T_DIM) {
      size_t ni = (size_t)(t + 2) * ST;
      xc0 = xpb[ni]; xc1 = xpb[ni + PO];
    }
    const uint32_t* hc = &hbuf[t & 1][0];
    float s0=0.f,s1=0.f,s2=0.f,s3=0.f,s4=0.f,s5=0.f,s6=0.f,s7=0.f;
    #pragma unroll
    for (int q = 0; q < 16; ++q) {
      uint4 hv0 = *(const uint4*)(hc + q*8);       // LDS broadcast (uniform addr)
      uint4 hv1 = *(const uint4*)(hc + q*8 + 4);
      s0 = __builtin_amdgcn_fdot2(wh[q*8+0], __builtin_bit_cast(f16x2, hv0.x), s0, false);
      s1 = __builtin_amdgcn_fdot2(wh[q*8+1], __builtin_bit_cast(f16x2, hv0.y), s1, false);
      s2 = __builtin_amdgcn_fdot2(wh[q*8+2], __builtin_bit_cast(f16x2, hv0.z), s2, false);
      s3 = __builtin_amdgcn_fdot2(wh[q*8+3], __builtin_bit_cast(f16x2, hv0.w), s3, false);
      s4 = __builtin_amdgcn_fdot2(wh[q*8+4], __builtin_bit_cast(f16x2, hv1.x), s4, false);
      s5 = __builtin_amdgcn_fdot2(wh[q*8+5], __builtin_bit_cast(f16x2, hv1.y), s5, false);
      s6 = __builtin_amdgcn_fdot2(wh[q*8+6], __builtin_bit_cast(f16x2, hv1.z), s6, false);
      s7 = __builtin_amdgcn_fdot2(wh[q*8+7], __builtin_bit_cast(f16x2, hv1.w), s7, false);
    }
    float pre = (xa0 + xa1) + bc + (((s0+s1)+(s2+s3)) + ((s4+s5)+(s6+s7)));
    float ax = fabsf(pre);
    float e2 = __expf(-2.f * ax);
    float r  = __fdividef(1.f - e2, 1.f + e2);
    float hn = (pre < 0.f) ? -r : r;
    ob[(size_t)t * ST] = hn;
    ((_Float16*)&hbuf[(t + 1) & 1][0])[l] = (_Float16)hn;
    __syncthreads();                               // single barrier per step
    xa0 = xb0; xa1 = xb1; xb0 = xc0; xb1 = xc1;
  }
}

extern "C" void kernel_launch(void* const* d_in, const int* in_sizes, int n_in,
                              void* d_out, int out_size, void* d_ws, size_t ws_size,
                              hipStream_t stream) {
  const float* x    = (const float*)d_in[0];
  const float* h0   = (const float*)d_in[1];
  const float* Wemb = (const float*)d_in[2];
  const float* bemb = (const float*)d_in[3];
  const float* Wenc = (const float*)d_in[4];
  const float* benc = (const float*)d_in[5];
  float* out = (float*)d_out;

  ushort* wct = (ushort*)d_ws;                               // 4 MiB bf16 [256][8192]
  float*  xp  = (float*)((char*)d_ws + ((size_t)4 << 20));   // 2 x 16 MiB fp32 partials

  wct_kernel<<<256, 256, 0, stream>>>(Wemb, Wenc, wct);
  gemm_kernel<<<256, 256, 0, stream>>>(x, wct, xp);
  rnn_kernel<<<64, 256, 0, stream>>>(xp, h0, Wenc, bemb, benc, out);
}